// Round 6
// baseline (592.065 us; speedup 1.0000x reference)
//
#include <hip/hip_runtime.h>
#include <cstdint>
#include <cstddef>

typedef __bf16 bf16_t;
typedef bf16_t bf16x8 __attribute__((ext_vector_type(8)));
typedef float floatx4 __attribute__((ext_vector_type(4)));
typedef unsigned long long u64;

#define B_   128
#define T_   64
#define H_   512
#define IN_  2048
#define FS_  1536
#define M_   (B_ * T_)   // 8192
#define GB_  64          // scan blocks (dispatched first => resident first)
#define PROD_ 384        // persistent GEMM producer blocks
#define JOBS_ 1280       // 64 slices * (12 gi-tiles + 8 gf-tiles)
#define SENT (~0ull)     // bf16 NaN sentinel — GRU outputs are never NaN

#define BM 128
#define BN 128
#define BK 32

// ---------------------------------------------------------------------------
__device__ __forceinline__ void async16(void* lds, const void* gp) {
  __builtin_amdgcn_global_load_lds(
      (const __attribute__((address_space(1))) void*)gp,
      (__attribute__((address_space(3))) void*)lds, 16, 0, 0);
}

// Agent-scope relaxed (coherent, MALL-served) ops. No fences (r2 lesson).
__device__ __forceinline__ u64 cload64(const u64* p) {
  return __hip_atomic_load((u64*)p, __ATOMIC_RELAXED, __HIP_MEMORY_SCOPE_AGENT);
}
__device__ __forceinline__ void cstore64(u64* p, u64 v) {
  __hip_atomic_store(p, v, __ATOMIC_RELAXED, __HIP_MEMORY_SCOPE_AGENT);
}
__device__ __forceinline__ int cloadi(const int* p) {
  return __hip_atomic_load((int*)p, __ATOMIC_RELAXED, __HIP_MEMORY_SCOPE_AGENT);
}
__device__ __forceinline__ void cstoref(float* p, float v) {
  __hip_atomic_store(p, v, __ATOMIC_RELAXED, __HIP_MEMORY_SCOPE_AGENT);
}
__device__ __forceinline__ void cstoreh(unsigned short* p, unsigned short v) {
  __hip_atomic_store(p, v, __ATOMIC_RELAXED, __HIP_MEMORY_SCOPE_AGENT);
}

__device__ __forceinline__ float fsigmoid(float x) {
  return __builtin_amdgcn_rcpf(1.f + __expf(-x));
}
__device__ __forceinline__ float ftanh(float x) {
  return 2.f * __builtin_amdgcn_rcpf(1.f + __expf(-2.f * x)) - 1.f;
}

// ---------------------------------------------------------------------------
// fp32 -> bf16, plain (weights)
__global__ __launch_bounds__(256) void cvt_bf16_k(const float* __restrict__ s,
                                                  bf16_t* __restrict__ d, int n8) {
  int i = blockIdx.x * 256 + threadIdx.x;
  if (i >= n8) return;
  const float4* s4 = (const float4*)s;
  float4 v0 = s4[2 * (size_t)i];
  float4 v1 = s4[2 * (size_t)i + 1];
  bf16x8 o;
  o[0] = (bf16_t)v0.x; o[1] = (bf16_t)v0.y; o[2] = (bf16_t)v0.z; o[3] = (bf16_t)v0.w;
  o[4] = (bf16_t)v1.x; o[5] = (bf16_t)v1.y; o[6] = (bf16_t)v1.z; o[7] = (bf16_t)v1.w;
  *(bf16x8*)(d + (size_t)i * 8) = o;
}

// fp32 [b][t][K] -> bf16 [t][b][K]  (t-major so one GEMM M-tile == one slice)
__global__ __launch_bounds__(256) void cvt_t_k(const float* __restrict__ s,
                                               bf16_t* __restrict__ d,
                                               int Kv, int n8) {
  int g = blockIdx.x * 256 + threadIdx.x;
  if (g >= n8) return;
  int kg = Kv >> 3;
  int k8 = g % kg;
  int row = g / kg;                 // b*T + t
  int b = row >> 6, t = row & 63;   // T_ = 64
  const float4* s4 = (const float4*)(s + (size_t)row * Kv + k8 * 8);
  float4 v0 = s4[0], v1 = s4[1];
  bf16x8 o;
  o[0] = (bf16_t)v0.x; o[1] = (bf16_t)v0.y; o[2] = (bf16_t)v0.z; o[3] = (bf16_t)v0.w;
  o[4] = (bf16_t)v1.x; o[5] = (bf16_t)v1.y; o[6] = (bf16_t)v1.z; o[7] = (bf16_t)v1.w;
  *(bf16x8*)(d + (size_t)(t * 128 + b) * Kv + k8 * 8) = o;
}

// ---------------------------------------------------------------------------
// UBER kernel: blocks [0,64) = persistent GRU scan; blocks [64,448) =
// persistent GEMM producers sweeping (t, n)-tiles in t-major order.
// Producers publish gi (fp32) / gf (fp16) slices with write-through stores,
// drain, then one agent atomicAdd on cnt[t]; slice ready when cnt[t]==20.
// Scan uses the r5 flagless NaN-sentinel h protocol (per-step buffers).
// All 448 blocks co-resident (50KB LDS -> 3 blocks/CU cap, 768 >= 448).
// ---------------------------------------------------------------------------
__global__ __launch_bounds__(256) void uber(
    const bf16_t* __restrict__ A1t, const bf16_t* __restrict__ A0t,
    const bf16_t* __restrict__ Wihb, const bf16_t* __restrict__ Wfhb,
    const float* __restrict__ b_ih, const float* __restrict__ b_fh,
    const float* __restrict__ Whh_f, const float* __restrict__ bhh,
    float* __restrict__ gi,          // [T][B][3H] fp32
    _Float16* __restrict__ gfh,      // [T][B][2H] fp16
    bf16_t* __restrict__ hbuf,       // 64 x 128KB, 0xFF-init
    int* __restrict__ cnt,           // [T] slice-ready counters (==20)
    float* __restrict__ out) {       // eo [B][T][H] ++ hT [B][H]
  __shared__ __align__(16) char smem[51200];
  const int tid  = threadIdx.x;
  const int lane = tid & 63;
  const int w    = tid >> 6;

  if (blockIdx.x >= GB_) {
    // =================== producer path ===================
    bf16_t* As = (bf16_t*)smem;             // 8 KB
    bf16_t* Bs = (bf16_t*)(smem + 8192);    // 8 KB
    const int wr = w >> 1, wc = w & 1;
    const int sr = lane >> 2;
    const int sc = (lane & 3) * 8;
    const int c0 = w * 2;
    const int fm = lane & 15;
    const int fk = (lane >> 4) * 8;
    const int pid = blockIdx.x - GB_;

    for (int job = pid; job < JOBS_; job += PROD_) {
      const int t = job / 20, sub = job % 20;
      const bool g1 = sub < 12;
      const int K = g1 ? IN_ : FS_;
      const int N = g1 ? 1536 : 1024;
      const int nblk = (g1 ? sub : sub - 12) * BN;
      const bf16_t* A  = (g1 ? A1t : A0t) + (size_t)t * 128 * K;
      const bf16_t* Bw = g1 ? Wihb : Wfhb;
      const float* bias = g1 ? b_ih : b_fh;

      const bf16_t* Ag0 = A + (size_t)(c0 * 16 + sr) * K + sc;
      const bf16_t* Ag1 = A + (size_t)(c0 * 16 + 16 + sr) * K + sc;
      const bf16_t* Bg0 = Bw + (size_t)(nblk + c0 * 16 + sr) * K + sc;
      const bf16_t* Bg1 = Bw + (size_t)(nblk + c0 * 16 + 16 + sr) * K + sc;
      bf16_t* As0 = As + c0 * 512;
      bf16_t* Bs0 = Bs + c0 * 512;

      floatx4 acc[4][4] = {};
      for (int kt = 0; kt < K; kt += BK) {
        async16(As0,       Ag0 + kt);
        async16(As0 + 512, Ag1 + kt);
        async16(Bs0,       Bg0 + kt);
        async16(Bs0 + 512, Bg1 + kt);
        __syncthreads();
        bf16x8 a[4], b[4];
#pragma unroll
        for (int i = 0; i < 4; i++)
          a[i] = *(const bf16x8*)(As + (wr * 64 + i * 16 + fm) * BK + fk);
#pragma unroll
        for (int j = 0; j < 4; j++)
          b[j] = *(const bf16x8*)(Bs + (wc * 64 + j * 16 + fm) * BK + fk);
#pragma unroll
        for (int i = 0; i < 4; i++)
#pragma unroll
          for (int j = 0; j < 4; j++)
            acc[i][j] = __builtin_amdgcn_mfma_f32_16x16x32_bf16(a[i], b[j], acc[i][j], 0, 0, 0);
        __syncthreads();
      }

      // epilogue: write-through stores (must reach MALL before cnt bump)
      const int en  = nblk + wc * 64 + fm;
      const int em0 = wr * 64 + (lane >> 4) * 4;
      if (g1) {
        float* C = gi + (size_t)t * 128 * 1536;
#pragma unroll
        for (int j = 0; j < 4; j++) {
          int col = en + j * 16;
          float bv = bias[col];
#pragma unroll
          for (int i = 0; i < 4; i++)
#pragma unroll
            for (int r = 0; r < 4; r++)
              cstoref(&C[(size_t)(em0 + i * 16 + r) * 1536 + col], acc[i][j][r] + bv);
        }
      } else {
        _Float16* C = gfh + (size_t)t * 128 * 1024;
#pragma unroll
        for (int j = 0; j < 4; j++) {
          int col = en + j * 16;
          float bv = bias[col];
#pragma unroll
          for (int i = 0; i < 4; i++)
#pragma unroll
            for (int r = 0; r < 4; r++) {
              _Float16 hv = (_Float16)(acc[i][j][r] + bv);
              cstoreh((unsigned short*)&C[(size_t)(em0 + i * 16 + r) * 1024 + col],
                      __builtin_bit_cast(unsigned short, hv));
            }
        }
      }
      asm volatile("s_waitcnt vmcnt(0)" ::: "memory");
      __syncthreads();   // every thread drained its stores
      if (tid == 0)
        __hip_atomic_fetch_add(cnt + t, 1, __ATOMIC_RELAXED, __HIP_MEMORY_SCOPE_AGENT);
    }
    return;
  }

  // =================== scan path ===================
  asm volatile("s_setprio 3" ::: );   // scan waves win issue arbitration
  bf16_t* wlds = (bf16_t*)smem;                 // 48 KB: W_hh frags
  bf16_t* swp  = (bf16_t*)(smem + 49152);       // 2 KB: repack scratch

  const int lm = lane & 15;
  const int lq = lane >> 4;
  const int c  = blockIdx.x >> 1;
  const int mh = blockIdx.x & 1;
  const int n0 = c * 16;

  // W_hh slice -> LDS in fragment order (once)
  for (int f = w; f < 48; f += 4) {
    int g = f >> 4, kt = f & 15;
    const float* src = Whh_f + (size_t)(g * H_ + n0 + lm) * H_ + kt * 32 + lq * 8;
    float4 v0 = *(const float4*)src;
    float4 v1 = *(const float4*)(src + 4);
    bf16x8 o;
    o[0] = (bf16_t)v0.x; o[1] = (bf16_t)v0.y; o[2] = (bf16_t)v0.z; o[3] = (bf16_t)v0.w;
    o[4] = (bf16_t)v1.x; o[5] = (bf16_t)v1.y; o[6] = (bf16_t)v1.z; o[7] = (bf16_t)v1.w;
    *(bf16x8*)(wlds + (f * 64 + lane) * 8) = o;
  }

  // publish zeros into step-0 h buffer
  {
    u64* z = (u64*)(hbuf + (((size_t)mh * 32 + c) * 64 + w * 16) * 16) + lane;
    cstore64(z, 0ull);
  }
  __syncthreads();   // wlds ready

  const float b0 = bhh[n0 + lm];
  const float b1 = bhh[H_ + n0 + lm];
  const float b2 = bhh[2 * H_ + n0 + lm];

  const int m0 = mh * 64 + w * 16;
  float hp[4] = {0.f, 0.f, 0.f, 0.f};

  float pir[4], pii[4], pin[4], pfr[4], pfi[4];
  auto prefetch = [&](int t) {
    // gate on slice-ready; then plain (cached) loads — data is at MALL,
    // consumer L2 is clean for these lines within this dispatch.
    while (cloadi(cnt + t) < 20) __builtin_amdgcn_s_sleep(1);
#pragma unroll
    for (int r = 0; r < 4; ++r) {
      int brow = m0 + lq * 4 + r;
      const float* gp = gi + ((size_t)t * 128 + brow) * 1536 + n0 + lm;
      pir[r] = gp[0];
      pii[r] = gp[512];
      pin[r] = gp[1024];
      const _Float16* fp = gfh + ((size_t)t * 128 + brow) * 1024 + n0 + lm;
      pfr[r] = (float)fp[0];
      pfi[r] = (float)fp[512];
    }
  };
  prefetch(0);

  const size_t habase = (size_t)mh * 32768 + ((size_t)w * 16 + lm) * 16 +
                        (size_t)(lq >> 1) * 1024 + (lq & 1) * 8;

  for (int t = 0; t < T_; ++t) {
    const bf16_t* hstep = hbuf + (size_t)t * 65536;
    union { u64 u[2]; bf16x8 v; } a[16];
    for (;;) {
      int ok = 1;
#pragma unroll
      for (int kt = 0; kt < 16; ++kt) {
        const u64* ap = (const u64*)(hstep + habase + (size_t)kt * 2048);
        a[kt].u[0] = cload64(ap);
        a[kt].u[1] = cload64(ap + 1);
      }
#pragma unroll
      for (int kt = 0; kt < 16; ++kt)
        ok &= (a[kt].u[0] != SENT) & (a[kt].u[1] != SENT);
      if (__all(ok)) break;
      __builtin_amdgcn_s_sleep(1);
    }

    floatx4 acc[3] = {};
#pragma unroll
    for (int g = 0; g < 3; ++g)
#pragma unroll
      for (int kt = 0; kt < 16; ++kt) {
        bf16x8 b = *(const bf16x8*)(wlds + ((g * 16 + kt) * 64 + lane) * 8);
        acc[g] = __builtin_amdgcn_mfma_f32_16x16x32_bf16(a[kt].v, b, acc[g], 0, 0, 0);
      }

    float hy[4];
#pragma unroll
    for (int r = 0; r < 4; ++r) {
      float rg = fsigmoid(pir[r] + acc[0][r] + b0 + pfr[r]);
      float ig = fsigmoid(pii[r] + acc[1][r] + b1 + pfi[r]);
      float ng = ftanh(pin[r] + rg * (acc[2][r] + b2));
      hy[r] = ng + ig * (hp[r] - ng);
      hp[r] = hy[r];
      swp[w * 256 + (lq * 4 + r) * 16 + lm] = (bf16_t)hy[r];
    }

    // publish ASAP (critical path)
    if (t + 1 < T_) {
      asm volatile("s_waitcnt lgkmcnt(0)" ::: "memory");
      u64 pk = *(const u64*)(swp + w * 256 + lane * 4);
      u64* dst = (u64*)(hbuf + (size_t)(t + 1) * 65536 +
                        (((size_t)mh * 32 + c) * 64 + w * 16) * 16) + lane;
      cstore64(dst, pk);
    }

    // off critical path: eo / hT stores, next-slice prefetch
#pragma unroll
    for (int r = 0; r < 4; ++r) {
      int brow = m0 + lq * 4 + r;
      size_t mrow = (size_t)brow * T_ + t;      // eo is [B][T][H]
      out[mrow * H_ + n0 + lm] = hy[r];
      if (t == T_ - 1)
        out[(size_t)M_ * H_ + (size_t)brow * H_ + n0 + lm] = hy[r];
    }
    if (t + 1 < T_) prefetch(t + 1);
  }
}

// ---------------------------------------------------------------------------
extern "C" void kernel_launch(void* const* d_in, const int* in_sizes, int n_in,
                              void* d_out, int out_size, void* d_ws, size_t ws_size,
                              hipStream_t stream) {
  const float* feat0 = (const float*)d_in[0];
  const float* feat1 = (const float*)d_in[1];
  const float* W_ih  = (const float*)d_in[2];
  const float* b_ih  = (const float*)d_in[3];
  const float* W_hh  = (const float*)d_in[4];
  const float* b_hh  = (const float*)d_in[5];
  const float* W_fh  = (const float*)d_in[6];
  const float* b_fh  = (const float*)d_in[7];
  float* out = (float*)d_out;

  char* p = (char*)d_ws;
  int*      cnt  = (int*)p;      p += 4096;                      // 64 counters
  bf16_t*   hbuf = (bf16_t*)p;   p += (size_t)T_ * 65536 * 2;    // 8 MB
  float*    gi   = (float*)p;    p += (size_t)M_ * 3 * H_ * 4;   // 48 MB
  _Float16* gfh  = (_Float16*)p; p += (size_t)M_ * 2 * H_ * 2;   // 16 MB
  bf16_t*   A1t  = (bf16_t*)p;   p += (size_t)M_ * IN_ * 2;      // 32 MB
  bf16_t*   A0t  = (bf16_t*)p;   p += (size_t)M_ * FS_ * 2;      // 24 MB
  bf16_t*   Wihb = (bf16_t*)p;   p += (size_t)3 * H_ * IN_ * 2;  // 6 MB
  bf16_t*   Wfhb = (bf16_t*)p;   p += (size_t)2 * H_ * FS_ * 2;  // 3 MB
  // total ~137 MB (< 147 MB known-good footprint from earlier rounds)

  hipMemsetAsync(cnt, 0, 4096, stream);
  hipMemsetAsync(hbuf, 0xFF, (size_t)T_ * 65536 * 2, stream);    // NaN sentinel

  // t-major bf16 activations
  {
    int n8 = M_ * IN_ / 8;
    cvt_t_k<<<(n8 + 255) / 256, 256, 0, stream>>>(feat1, A1t, IN_, n8);
  }
  {
    int n8 = M_ * FS_ / 8;
    cvt_t_k<<<(n8 + 255) / 256, 256, 0, stream>>>(feat0, A0t, FS_, n8);
  }
  // weights
  {
    int n8 = 3 * H_ * IN_ / 8;
    cvt_bf16_k<<<(n8 + 255) / 256, 256, 0, stream>>>(W_ih, Wihb, n8);
  }
  {
    int n8 = 2 * H_ * FS_ / 8;
    cvt_bf16_k<<<(n8 + 255) / 256, 256, 0, stream>>>(W_fh, Wfhb, n8);
  }

  uber<<<GB_ + PROD_, 256, 0, stream>>>(A1t, A0t, Wihb, Wfhb, b_ih, b_fh,
                                        W_hh, b_hh, gi, gfh, hbuf, cnt, out);
}